// Round 1
// 130.307 us; speedup vs baseline: 1.0007x; 1.0007x over previous
//
#include <hip/hip_runtime.h>

// Submanifold sparse conv — 3 dispatches (R4 lesson: grid barriers on MI355X
// cost per-XCD L2 wb/inv storms; never again).
//   1. hipMemsetAsync grid+bitmap to 0
//   2. build_grid: atomicMax(grid[key], n-i) + atomicOr(bitmap bit)
//      (empty=0; max(n-i) == min index, matching reference's stable-argsort
//      duplicate resolution)
//   3. conv: block = 64 points, block-local rulebook in LDS:
//        P0 stage: pos rows for the block -> LDS (coalesced, kills scattered
//           pos re-reads in P1)
//        P1 probe via OCCUPANCY BITMAP (275 KB = 130^3 bits, fully L2-resident
//           per XCD vs the 8.8 MB index grid that thrashes 4 MB L2): one
//           (pt, dx,dy) item = two 4B bitmap words -> z-1/z/z+1 triple in one
//           go. Only actual hits (~2.24/27) fetch the 4B index from the big
//           grid. Probe loads: 2.7M x 4B random-in-8.8MB  ->  0.9M x 8B
//           L2-hot + ~225k index fetches. Hits appended to per-offset LDS
//           lists via LDS atomics (R2: global same-line atomics ~2ns/op).
//        P2 center: W13 column in 32 VGPRs, float4 gathers, plain writes to
//           LDS acc tile [64][32] (doubles as acc init)
//        P3 drain: wave w handles offsets o=w,w+4,...; W[o] column loaded ONCE
//           per (block,offset) into 32 VGPRs (weight L1 traffic 900MB -> 170MB
//           vs R1), half-wave per pair, float4 feature broadcasts, ds_add_f32
//           into acc tile. All out-writes are block-owned -> no global atomics.
//        P4 write-out: coalesced plain stores.

#define GRID_B 130
#define GRID_CELLS 2197000      // 130^3
#define BM_WORDS 68704          // ceil(130^3 / 32) = 68657, padded so w+1 reads stay in-bounds
#define C 32
#define NTHR 256
#define PTS 64                  // points per block
#define CAP 24                  // per-offset list cap (Binom(64,0.048); P(>24) ~ 1e-13)

__global__ void build_grid_kernel(const int* __restrict__ pos,
                                  int* __restrict__ grid,
                                  unsigned int* __restrict__ bm, int n) {
    int i = blockIdx.x * blockDim.x + threadIdx.x;
    if (i >= n) return;
    int x = pos[3 * i + 0] + 1;
    int y = pos[3 * i + 1] + 1;
    int z = pos[3 * i + 2] + 1;
    int key = (x * GRID_B + y) * GRID_B + z;
    atomicMax(&grid[key], n - i);
    atomicOr(&bm[key >> 5], 1u << (key & 31));
}

__global__ __launch_bounds__(NTHR)
void conv_kernel(const float* __restrict__ feat,
                 const int* __restrict__ pos,
                 const float* __restrict__ w,
                 const int* __restrict__ grid,
                 const unsigned int* __restrict__ bm,
                 float* __restrict__ out, int n) {
    __shared__ int   s_cnt[27];
    __shared__ int   s_list[27][CAP];     // packed (pt_local<<17) | j
    __shared__ int   s_rep[PTS];          // center neighbor (min-dup index)
    __shared__ int   s_pos[PTS * 3];      // staged positions
    __shared__ float s_acc[PTS][C];       // 8 KB accumulator tile

    const int tid = threadIdx.x;
    const int pt_base = blockIdx.x * PTS;

    if (tid < 27) s_cnt[tid] = 0;
    // ---- P0: stage the block's positions (coalesced) ----
    for (int u = tid; u < PTS * 3; u += NTHR) {
        int g = pt_base * 3 + u;
        if (g < n * 3) s_pos[u] = pos[g];
    }
    __syncthreads();

    // ---- P1: 64 pts x 9 (dx,dy) columns; bitmap gives the z-triple ----
    for (int t = tid; t < PTS * 9; t += NTHR) {
        int pl = t / 9;                  // const-div -> magic mul
        int xy = t - pl * 9;
        if (pt_base + pl < n) {
            int dx = xy / 3;             // 0..2
            int dy = xy - dx * 3;        // 0..2
            int x0 = s_pos[pl * 3 + 0] + dx;         // (x+1) + (dx-1)
            int y0 = s_pos[pl * 3 + 1] + dy;
            // key of (x0, y0, z-1): z base = pos.z (+1 shift, -1 offset)
            int k0 = (x0 * GRID_B + y0) * GRID_B + s_pos[pl * 3 + 2];
            unsigned int w0 = bm[(k0 >> 5)];
            unsigned int w1 = bm[(k0 >> 5) + 1];     // L2-hot, usually same line
            unsigned int bits =
                (unsigned int)((((unsigned long long)w1 << 32) | w0) >> (k0 & 31)) & 7u;
            int obase = xy * 3;          // o = (dx*3+dy)*3 + oz
            if (xy == 4) {
                // center column: own voxel always occupied -> read rep index
                s_rep[pl] = n - grid[k0 + 1];
                bits &= 5u;              // dz=-1 / dz=+1 handled below
            }
            while (bits) {               // ~0.3 hits per item on average
                int oz = __ffs(bits) - 1;
                bits &= bits - 1;
                int v = grid[k0 + oz];   // index fetch only for real hits
                int slot = atomicAdd(&s_cnt[obase + oz], 1);
                if (slot < CAP) s_list[obase + oz][slot] = (pl << 17) | (n - v);
            }
        }
    }
    __syncthreads();

    // ---- P2: center contribution -> initializes s_acc (plain writes) ----
    {
        const int cout = tid & 31;
        float wreg[32];
        #pragma unroll
        for (int c = 0; c < 32; ++c) wreg[c] = w[13 * 1024 + c * 32 + cout];
        for (int u = tid; u < PTS * C; u += NTHR) {    // u&31 == cout (NTHR%32==0)
            int pl = u >> 5;
            if (pt_base + pl < n) {
                const float4* __restrict__ f4 = (const float4*)(feat + (size_t)s_rep[pl] * C);
                float acc = 0.0f;
                #pragma unroll
                for (int k = 0; k < 8; ++k) {
                    float4 fv = f4[k];
                    acc = fmaf(fv.x, wreg[4 * k + 0], acc);
                    acc = fmaf(fv.y, wreg[4 * k + 1], acc);
                    acc = fmaf(fv.z, wreg[4 * k + 2], acc);
                    acc = fmaf(fv.w, wreg[4 * k + 3], acc);
                }
                s_acc[pl][cout] = acc;
            }
        }
    }
    __syncthreads();

    // ---- P3: drain per-offset lists; W[o] column amortized over the list ----
    {
        const int wv = tid >> 6;          // wave 0..3
        const int lane = tid & 63;
        const int cout = lane & 31;
        const int half = lane >> 5;
        for (int o = wv; o < 27; o += 4) {
            if (o == 13) continue;
            int cnt = min(s_cnt[o], CAP);
            if (cnt == 0) continue;
            float wreg[32];
            #pragma unroll
            for (int c = 0; c < 32; ++c) wreg[c] = w[o * 1024 + c * 32 + cout];
            for (int e = half; e < cnt; e += 2) {      // 2 pairs per wave iter
                int packed = s_list[o][e];             // LDS same-addr broadcast
                int pl = packed >> 17;
                int j  = packed & 0x1FFFF;
                const float4* __restrict__ f4 = (const float4*)(feat + (size_t)j * C);
                float acc = 0.0f;
                #pragma unroll
                for (int k = 0; k < 8; ++k) {
                    float4 fv = f4[k];
                    acc = fmaf(fv.x, wreg[4 * k + 0], acc);
                    acc = fmaf(fv.y, wreg[4 * k + 1], acc);
                    acc = fmaf(fv.z, wreg[4 * k + 2], acc);
                    acc = fmaf(fv.w, wreg[4 * k + 3], acc);
                }
                atomicAdd(&s_acc[pl][cout], acc);      // ds_add_f32, banks 0..31 clean
            }
        }
    }
    __syncthreads();

    // ---- P4: coalesced write-out (block owns its 64 points exclusively) ----
    {
        const int base = pt_base * C;
        const int lim = n * C - base;                  // last block: exactly 1024
        for (int u = tid; u < PTS * C && u < lim; u += NTHR)
            out[base + u] = s_acc[u >> 5][u & 31];
    }
}

extern "C" void kernel_launch(void* const* d_in, const int* in_sizes, int n_in,
                              void* d_out, int out_size, void* d_ws, size_t ws_size,
                              hipStream_t stream) {
    const float* features = (const float*)d_in[0];
    const int*   positions = (const int*)d_in[1];
    const float* weight = (const float*)d_in[2];
    float* out = (float*)d_out;
    const int n = in_sizes[0] / C;       // 100000

    int* grid = (int*)d_ws;
    unsigned int* bm = (unsigned int*)(grid + GRID_CELLS);
    hipMemsetAsync(d_ws, 0, (size_t)(GRID_CELLS + BM_WORDS) * sizeof(int), stream);

    build_grid_kernel<<<(n + 255) / 256, 256, 0, stream>>>(positions, grid, bm, n);

    conv_kernel<<<(n + PTS - 1) / PTS, NTHR, 0, stream>>>(features, positions, weight,
                                                          grid, bm, out, n);
}